// Round 1
// baseline (498.325 us; speedup 1.0000x reference)
//
#include <hip/hip_runtime.h>
#include <hip/hip_bf16.h>
#include <stdint.h>

// Problem: B=64, L=1024, V=1024, H=512, A=512
// out[0:65536)   = att_output [64][1024] fp32
// out[65536:...) = att_scores [64][1024] fp32

typedef __attribute__((ext_vector_type(8))) short bf16x8;
typedef __attribute__((ext_vector_type(8))) unsigned short ushortx8;
typedef __attribute__((ext_vector_type(4))) float f32x4;

#define LOG2E 1.4426950408889634f

__device__ __forceinline__ unsigned short f2bf(float f) {
  uint32_t u = __builtin_bit_cast(uint32_t, f);
  u += 0x7FFFu + ((u >> 16) & 1u);   // round-to-nearest-even
  return (unsigned short)(u >> 16);
}

__device__ __forceinline__ float fast_tanh(float x) {
  // tanh(x) = 1 - 2/(exp(2x)+1); exp via native exp2
  float e = __builtin_amdgcn_exp2f(x * 2.885390081777927f);  // 2*log2(e)
  return 1.0f - 2.0f * __builtin_amdgcn_rcpf(e + 1.0f);
}

__device__ __forceinline__ void load_lds16(const void* g, void* l) {
  __builtin_amdgcn_global_load_lds(
      (const __attribute__((address_space(1))) void*)g,
      (__attribute__((address_space(3))) void*)l, 16, 0, 0);
}

// K0: pack W_enc [1024v][512a] fp32 -> Wst bf16 in per-K-step staged slot order.
// Slot S (16B = 8 bf16): t = S>>11 (K-step of 32), s = S&2047, a = s>>2, kb = s&3.
// Content: W_enc[t*32 + kb*8 + j][a], j = 0..7 (contiguous in K).
__global__ __launch_bounds__(256) void k0_pack_w(const float* __restrict__ W,
                                                 unsigned short* __restrict__ Wst) {
  const int S = blockIdx.x * 256 + threadIdx.x;  // 65536 slots
  const int t = S >> 11;
  const int s = S & 2047;
  const int a = s >> 2;
  const int kb = s & 3;
  const int k0 = t * 32 + kb * 8;
  ushortx8 p;
#pragma unroll
  for (int j = 0; j < 8; ++j) p[j] = f2bf(W[(size_t)(k0 + j) * 512 + a]);
  *(ushortx8*)(Wst + (size_t)S * 8) = p;
}

// K1: dproj[b][a] = dec[b,:]@W_dec[:,a] + b_dec[a] + b_enc[a]; also zero logits.
__global__ __launch_bounds__(256) void k1_dproj(const float* __restrict__ dec,
                                                const float* __restrict__ Wd,
                                                const float* __restrict__ bd,
                                                const float* __restrict__ be,
                                                float* __restrict__ dproj,
                                                float* __restrict__ logits) {
  const int b = blockIdx.x;
  const int tid = threadIdx.x;
#pragma unroll
  for (int j = 0; j < 4; ++j) logits[b * 1024 + j * 256 + tid] = 0.0f;
  float a0 = 0.f, a1 = 0.f;
  const float* dr = dec + b * 512;
  for (int h = 0; h < 512; ++h) {
    float d = dr[h];
    a0 = fmaf(d, Wd[h * 512 + tid], a0);
    a1 = fmaf(d, Wd[h * 512 + tid + 256], a1);
  }
  dproj[b * 512 + tid] = a0 + bd[tid] + be[tid];
  dproj[b * 512 + tid + 256] = a1 + bd[tid + 256] + be[tid + 256];
}

// K2: fused  logits[b,l] = sum_a w_full[a]*tanh( (vis@W_enc)[b,l,a] + dproj[b,a] )
// Tile: 64 M-rows x 512 N (all of A) per block, 4 waves, wave = 64x128.
// bf16 MFMA 16x16x32, K-step 32, double-buffered LDS, 2-phase single barrier.
__global__ __launch_bounds__(256, 2) void k2_fused_gemm(
    const float* __restrict__ vis, const unsigned short* __restrict__ Wst,
    const float* __restrict__ dproj, const float* __restrict__ wfull,
    float* __restrict__ logits) {
  alignas(16) __shared__ unsigned short Al[2][2048];    // [buf][kb*512 + row*8]  (4KB/buf)
  alignas(16) __shared__ unsigned short Bl[2][16384];   // [buf][(a*4+kb)*8]      (32KB/buf)

  const int tid = threadIdx.x;
  const int lane = tid & 63;
  const int w = tid >> 6;                 // wave 0..3 -> cols [w*128, +128)
  const int blk = blockIdx.x;             // 0..1023, rows [blk*64, +64)
  const int b = blk >> 4;                 // 16 blocks per batch row
  const size_t mbase = (size_t)blk * 64;

  // A staging: thread -> (row = tid>>2, kb = tid&3); reads 8 fp32, writes 1x16B
  const int arow = tid >> 2;
  const int akb = tid & 3;
  const float* asrc = vis + (mbase + (size_t)arow) * 1024 + akb * 8;
  const int a_dst = akb * 512 + arow * 8;  // ushort offset in Al[buf]

  // B staging: wave w covers slots [w*512, +512) = a in [w*128,(w+1)*128)
  const unsigned short* bsrc = Wst + (size_t)w * 4096 + (size_t)lane * 8;

  f32x4 acc[4][8];
#pragma unroll
  for (int m = 0; m < 4; ++m)
#pragma unroll
    for (int n = 0; n < 8; ++n) acc[m][n] = (f32x4){0.f, 0.f, 0.f, 0.f};

  auto stage = [&](int t, int buf) {
    const unsigned short* bs = bsrc + (size_t)t * 16384;
#pragma unroll
    for (int j = 0; j < 8; ++j)
      load_lds16(bs + j * 512, &Bl[buf][w * 4096 + j * 512]);
    const float* as = asrc + (size_t)t * 32;
    f32x4 x0 = *(const f32x4*)(as);
    f32x4 x1 = *(const f32x4*)(as + 4);
    ushortx8 p;
    p[0] = f2bf(x0[0]); p[1] = f2bf(x0[1]); p[2] = f2bf(x0[2]); p[3] = f2bf(x0[3]);
    p[4] = f2bf(x1[0]); p[5] = f2bf(x1[1]); p[6] = f2bf(x1[2]); p[7] = f2bf(x1[3]);
    *(ushortx8*)(&Al[buf][a_dst]) = p;
  };

  stage(0, 0);

  // frag read offsets (ushort units)
  const int a_rd = (lane >> 4) * 512 + (lane & 15) * 8;               // + m*128
  const int b_rd = w * 4096 + (lane & 15) * 32 + (lane >> 4) * 8;     // + n*512

  for (int t = 0; t < 32; ++t) {
    const int cur = t & 1;
    __syncthreads();                       // buf[cur] staged (drains vmcnt+lgkm)
    if (t < 31) stage(t + 1, cur ^ 1);     // issue next-tile loads; overlap MFMA
    bf16x8 af[4];
#pragma unroll
    for (int m = 0; m < 4; ++m) af[m] = *(const bf16x8*)(&Al[cur][a_rd + m * 128]);
    bf16x8 bfr[8];
#pragma unroll
    for (int n = 0; n < 8; ++n) bfr[n] = *(const bf16x8*)(&Bl[cur][b_rd + n * 512]);
#pragma unroll
    for (int m = 0; m < 4; ++m)
#pragma unroll
      for (int n = 0; n < 8; ++n)
        acc[m][n] = __builtin_amdgcn_mfma_f32_16x16x32_bf16(af[m], bfr[n], acc[m][n], 0, 0, 0);
  }

  // Epilogue: C/D layout col = lane&15, row = (lane>>4)*4 + reg (m89-verified).
  // lane holds D[row=16m+(lane>>4)*4+r][col=w*128+16n+(lane&15)]
  const float* dp = dproj + b * 512 + w * 128 + (lane & 15);
  const float* wf = wfull + w * 128 + (lane & 15);
  float dpv[8], wfv[8];
#pragma unroll
  for (int n = 0; n < 8; ++n) { dpv[n] = dp[n * 16]; wfv[n] = wf[n * 16]; }

#pragma unroll
  for (int m = 0; m < 4; ++m) {
#pragma unroll
    for (int r = 0; r < 4; ++r) {
      float s = 0.f;
#pragma unroll
      for (int n = 0; n < 8; ++n)
        s += wfv[n] * fast_tanh(acc[m][n][r] + dpv[n]);
      // reduce over the 16 lanes sharing this row (lane&15 = col)
      s += __shfl_xor(s, 1, 64);
      s += __shfl_xor(s, 2, 64);
      s += __shfl_xor(s, 4, 64);
      s += __shfl_xor(s, 8, 64);
      if ((lane & 15) == 0) {
        int row = m * 16 + (lane >> 4) * 4 + r;
        atomicAdd(&logits[mbase + row], s);   // 4 waves add their 128-col partials
      }
    }
  }
}

// K3: per-b softmax over L=1024; writes scores to out[65536+...], zeros att_output.
__global__ __launch_bounds__(256) void k3_softmax(const float* __restrict__ logits,
                                                  float* __restrict__ out) {
  const int b = blockIdx.x;
  const int tid = threadIdx.x;
#pragma unroll
  for (int j = 0; j < 4; ++j) out[b * 1024 + j * 256 + tid] = 0.f;  // zero att_output

  float x[4];
#pragma unroll
  for (int j = 0; j < 4; ++j) x[j] = logits[b * 1024 + j * 256 + tid];
  float mx = fmaxf(fmaxf(x[0], x[1]), fmaxf(x[2], x[3]));
#pragma unroll
  for (int d = 1; d < 64; d <<= 1) mx = fmaxf(mx, __shfl_xor(mx, d, 64));
  __shared__ float redm[4], reds[4];
  if ((tid & 63) == 0) redm[tid >> 6] = mx;
  __syncthreads();
  mx = fmaxf(fmaxf(redm[0], redm[1]), fmaxf(redm[2], redm[3]));
  float e[4];
  float s = 0.f;
#pragma unroll
  for (int j = 0; j < 4; ++j) {
    e[j] = __builtin_amdgcn_exp2f((x[j] - mx) * LOG2E);
    s += e[j];
  }
#pragma unroll
  for (int d = 1; d < 64; d <<= 1) s += __shfl_xor(s, d, 64);
  if ((tid & 63) == 0) reds[tid >> 6] = s;
  __syncthreads();
  s = reds[0] + reds[1] + reds[2] + reds[3];
  float inv = 1.0f / s;
#pragma unroll
  for (int j = 0; j < 4; ++j) out[65536 + b * 1024 + j * 256 + tid] = e[j] * inv;
}

// K4: att_output[b][v] += sum_{l in chunk} scores[b][l] * vis[b][l][v]
// grid (64 b, 8 chunks of 128 l); thread owns one float4 of v; fp32 atomics.
__global__ __launch_bounds__(256) void k4_attout(const float* __restrict__ vis,
                                                 const float* __restrict__ scores,
                                                 float* __restrict__ out) {
  const int b = blockIdx.x;
  const int chunk = blockIdx.y;
  const int tid = threadIdx.x;
  const float* sc = scores + b * 1024 + chunk * 128;
  const f32x4* vbase = (const f32x4*)(vis + ((size_t)b * 1024 + (size_t)chunk * 128) * 1024) + tid;
  f32x4 acc = (f32x4){0.f, 0.f, 0.f, 0.f};
  for (int l = 0; l < 128; ++l) {
    float s = sc[l];
    f32x4 v = vbase[(size_t)l * 256];
    acc += v * s;
  }
  float* o = out + b * 1024 + tid * 4;
  atomicAdd(o + 0, acc[0]);
  atomicAdd(o + 1, acc[1]);
  atomicAdd(o + 2, acc[2]);
  atomicAdd(o + 3, acc[3]);
}

extern "C" void kernel_launch(void* const* d_in, const int* in_sizes, int n_in,
                              void* d_out, int out_size, void* d_ws, size_t ws_size,
                              hipStream_t stream) {
  const float* vis = (const float*)d_in[0];    // [64][1024][1024]
  const float* dec = (const float*)d_in[1];    // [64][512]
  const float* Wenc = (const float*)d_in[2];   // [1024][512]
  const float* benc = (const float*)d_in[3];   // [512]
  const float* Wdec = (const float*)d_in[4];   // [512][512]
  const float* bdec = (const float*)d_in[5];   // [512]
  const float* wfull = (const float*)d_in[6];  // [512]
  // d_in[7] = b_full: softmax-shift-invariant -> unused.
  float* out = (float*)d_out;                  // [65536 att_output | 65536 att_scores]
  char* ws = (char*)d_ws;
  unsigned short* Wst = (unsigned short*)ws;               // 1 MB bf16-packed W_enc^T
  float* dproj = (float*)(ws + (1 << 20));                 // 128 KB
  float* logits = (float*)(ws + (1 << 20) + (128 << 10));  // 256 KB

  hipLaunchKernelGGL(k0_pack_w, dim3(256), dim3(256), 0, stream, Wenc, Wst);
  hipLaunchKernelGGL(k1_dproj, dim3(64), dim3(256), 0, stream, dec, Wdec, bdec, benc, dproj, logits);
  hipLaunchKernelGGL(k2_fused_gemm, dim3(1024), dim3(256), 0, stream, vis, Wst, dproj, wfull, logits);
  hipLaunchKernelGGL(k3_softmax, dim3(64), dim3(256), 0, stream, logits, out);
  hipLaunchKernelGGL(k4_attout, dim3(64, 8), dim3(256), 0, stream, vis, out + 65536, out);
}

// Round 2
// 488.978 us; speedup vs baseline: 1.0191x; 1.0191x over previous
//
#include <hip/hip_runtime.h>
#include <hip/hip_bf16.h>
#include <stdint.h>

// Problem: B=64, L=1024, V=1024, H=512, A=512
// out[0:65536)   = att_output [64][1024] fp32
// out[65536:...) = att_scores [64][1024] fp32

typedef __attribute__((ext_vector_type(8))) short bf16x8;
typedef __attribute__((ext_vector_type(8))) unsigned short ushortx8;
typedef __attribute__((ext_vector_type(4))) float f32x4;

#define LOG2E 1.4426950408889634f

__device__ __forceinline__ unsigned short f2bf(float f) {
  uint32_t u = __builtin_bit_cast(uint32_t, f);
  u += 0x7FFFu + ((u >> 16) & 1u);   // round-to-nearest-even
  return (unsigned short)(u >> 16);
}

__device__ __forceinline__ float fast_tanh(float x) {
  // tanh(x) = 1 - 2/(exp(2x)+1); exp via native exp2
  float e = __builtin_amdgcn_exp2f(x * 2.885390081777927f);  // 2*log2(e)
  return 1.0f - 2.0f * __builtin_amdgcn_rcpf(e + 1.0f);
}

__device__ __forceinline__ void load_lds16(const void* g, void* l) {
  __builtin_amdgcn_global_load_lds(
      (const __attribute__((address_space(1))) void*)g,
      (__attribute__((address_space(3))) void*)l, 16, 0, 0);
}

// ---------------------------------------------------------------------------
// K01: prep kernel, grid 512.
//  blocks [0,256):  pack W_enc [1024k][512a] fp32 -> Wst bf16, layout [t][kb][a]:
//                   slot S: t=S>>11, kb=(S>>9)&3, a=S&511; content = W[t*32+kb*8+j][a], j=0..7
//  blocks [256,512): q = blk-256: zero logits[q*256+..] and out[q*256+..];
//                   dproj[b][a] for b=q>>2, a in [(q&3)*128, +128)
// ---------------------------------------------------------------------------
__global__ __launch_bounds__(256) void k01_prep(const float* __restrict__ W,
                                                unsigned short* __restrict__ Wst,
                                                const float* __restrict__ dec,
                                                const float* __restrict__ Wd,
                                                const float* __restrict__ bd,
                                                const float* __restrict__ be,
                                                float* __restrict__ dproj,
                                                float* __restrict__ logits,
                                                float* __restrict__ out) {
  const int tid = threadIdx.x;
  if (blockIdx.x < 256) {
    const int S = blockIdx.x * 256 + tid;  // 65536 slots
    const int t = S >> 11;
    const int kb = (S >> 9) & 3;
    const int a = S & 511;
    const int k0 = t * 32 + kb * 8;
    ushortx8 p;
#pragma unroll
    for (int j = 0; j < 8; ++j) p[j] = f2bf(W[(size_t)(k0 + j) * 512 + a]);
    *(ushortx8*)(Wst + (size_t)S * 8) = p;
  } else {
    const int q = blockIdx.x - 256;  // 0..255
    logits[q * 256 + tid] = 0.0f;
    out[q * 256 + tid] = 0.0f;       // zero att_output for k34's atomics
    const int b = q >> 2;
    const int a = (q & 3) * 128 + (tid & 127);
    const int hh = tid >> 7;         // 2 h-halves of 256
    const float* dr = dec + b * 512 + hh * 256;
    const float* wc = Wd + (size_t)(hh * 256) * 512 + a;
    float acc = 0.f;
#pragma unroll 8
    for (int h = 0; h < 256; ++h) acc = fmaf(dr[h], wc[(size_t)h * 512], acc);
    __shared__ float sh[128];
    if (hh == 1) sh[tid & 127] = acc;
    __syncthreads();
    if (hh == 0) dproj[b * 512 + a] = acc + sh[tid] + bd[a] + be[a];
  }
}

// ---------------------------------------------------------------------------
// K2: fused  logits[b,l] = sum_a w_full[a]*tanh( (vis@W_enc)[b,l,a] + dproj[b,a] )
// Tile: 128 M-rows x 512 N per block, 512 threads = 8 waves (2 wm x 4 wn),
// wave tile 64x128. bf16 MFMA 16x16x32, K-step 32, double-buffered LDS.
// A: depth-2 register prefetch (HBM latency hidden over a full iteration);
// B: global_load_lds from L2-resident packed Wst.
// LDS layouts (conflict-free 16B lane stride):
//   Al[buf][kb*1024 + row*8]   (128 rows, 4 kb)   8KB/buf
//   Bl[buf][kb*4096 + a*8]     (512 a,   4 kb)   32KB/buf   => 80KB total
// ---------------------------------------------------------------------------
__global__ __launch_bounds__(512, 1) void k2_fused_gemm(
    const float* __restrict__ vis, const unsigned short* __restrict__ Wst,
    const float* __restrict__ dproj, const float* __restrict__ wfull,
    float* __restrict__ logits) {
  alignas(16) __shared__ unsigned short Al[2][4096];
  alignas(16) __shared__ unsigned short Bl[2][16384];

  const int tid = threadIdx.x;
  const int lane = tid & 63;
  const int w = tid >> 6;            // 0..7
  const int wm = w >> 2;             // 0..1: rows [wm*64, +64)
  const int wn = w & 3;              // 0..3: cols [wn*128, +128)
  const int blk = blockIdx.x;        // 0..511, rows [blk*128, +128)
  const int b = blk >> 3;
  const size_t mbase = (size_t)blk * 128;

  // A staging: thread -> (row = tid>>2, kb = tid&3)
  const int arow = tid >> 2;
  const int akb = tid & 3;
  const float* asrc = vis + (mbase + (size_t)arow) * 1024 + akb * 8;
  const int a_dst = akb * 1024 + arow * 8;  // ushort offset in Al[buf]

  // B staging: wave w stages slots [w*256, +256) per K-step (4 x load_lds16)
  const unsigned short* bsrc = Wst + (size_t)w * 2048 + (size_t)lane * 8;

  f32x4 acc[4][8];
#pragma unroll
  for (int m = 0; m < 4; ++m)
#pragma unroll
    for (int n = 0; n < 8; ++n) acc[m][n] = (f32x4){0.f, 0.f, 0.f, 0.f};

  auto bload = [&](int t, int buf) {
    const unsigned short* bs = bsrc + (size_t)t * 16384;
#pragma unroll
    for (int j = 0; j < 4; ++j)
      load_lds16(bs + j * 512, &Bl[buf][w * 2048 + j * 512]);
  };
  auto aload = [&](int t, f32x4* x) {
    const float* as = asrc + (size_t)t * 32;
    x[0] = *(const f32x4*)(as);
    x[1] = *(const f32x4*)(as + 4);
  };
  auto awrite = [&](int buf, const f32x4* x) {
    ushortx8 p;
    p[0] = f2bf(x[0][0]); p[1] = f2bf(x[0][1]); p[2] = f2bf(x[0][2]); p[3] = f2bf(x[0][3]);
    p[4] = f2bf(x[1][0]); p[5] = f2bf(x[1][1]); p[6] = f2bf(x[1][2]); p[7] = f2bf(x[1][3]);
    *(ushortx8*)(&Al[buf][a_dst]) = p;
  };

  // frag read offsets (ushort units)
  const int a_rd = (lane >> 4) * 1024 + (wm * 64 + (lane & 15)) * 8;   // + m*128
  const int b_rd = (lane >> 4) * 4096 + (wn * 128 + (lane & 15)) * 8;  // + n*128

  f32x4 xA[2], xB[2];
  // prologue: stage tile 0 directly; load tile 1 into regs
  bload(0, 0);
  aload(0, xA);
  awrite(0, xA);
  aload(1, xA);  // xA now holds tile-1 data

  auto step = [&](int t, int cur, f32x4* xc, f32x4* xn) {
    __syncthreads();                       // buf[cur] staged
    if (t < 31) bload(t + 1, cur ^ 1);     // B for next tile (L2, ~200cy)
    if (t < 30) aload(t + 2, xn);          // A for tile t+2 (HBM, lands next iter)
    bf16x8 af[4];
#pragma unroll
    for (int m = 0; m < 4; ++m) af[m] = *(const bf16x8*)(&Al[cur][a_rd + m * 128]);
    bf16x8 bfr[8];
#pragma unroll
    for (int n = 0; n < 8; ++n) bfr[n] = *(const bf16x8*)(&Bl[cur][b_rd + n * 128]);
#pragma unroll
    for (int m = 0; m < 4; ++m)
#pragma unroll
      for (int n = 0; n < 8; ++n)
        acc[m][n] = __builtin_amdgcn_mfma_f32_16x16x32_bf16(af[m], bfr[n], acc[m][n], 0, 0, 0);
    if (t < 31) awrite(cur ^ 1, xc);       // ds_write lands before next barrier
  };

  for (int tt = 0; tt < 32; tt += 2) {
    step(tt, 0, xA, xB);
    step(tt + 1, 1, xB, xA);
  }

  // Epilogue: C/D layout col = lane&15, row = (lane>>4)*4 + reg (m89-verified).
  // lane holds D[row = wm*64 + 16m + (lane>>4)*4 + r][col = wn*128 + 16n + (lane&15)]
  const float* dp = dproj + b * 512 + wn * 128 + (lane & 15);
  const float* wf = wfull + wn * 128 + (lane & 15);
  float dpv[8], wfv[8];
#pragma unroll
  for (int n = 0; n < 8; ++n) { dpv[n] = dp[n * 16]; wfv[n] = wf[n * 16]; }

#pragma unroll
  for (int m = 0; m < 4; ++m) {
#pragma unroll
    for (int r = 0; r < 4; ++r) {
      float s = 0.f;
#pragma unroll
      for (int n = 0; n < 8; ++n)
        s += wfv[n] * fast_tanh(acc[m][n][r] + dpv[n]);
      // reduce over the 16 lanes sharing this row (lane&15 = col)
      s += __shfl_xor(s, 1, 64);
      s += __shfl_xor(s, 2, 64);
      s += __shfl_xor(s, 4, 64);
      s += __shfl_xor(s, 8, 64);
      if ((lane & 15) == 0) {
        int row = wm * 64 + m * 16 + (lane >> 4) * 4 + r;
        atomicAdd(&logits[mbase + row], s);   // 4 wn-waves add their 128-col partials
      }
    }
  }
}

// ---------------------------------------------------------------------------
// K34: fused softmax + weighted sum. grid (64 b, 8 chunks of 128 l).
// Each block recomputes the row max/sum from logits (4KB, L2-hot), chunk-0
// blocks write att_scores; all blocks atomically accumulate att_output.
// ---------------------------------------------------------------------------
__global__ __launch_bounds__(256) void k34_attout(const float* __restrict__ logits,
                                                  const float* __restrict__ vis,
                                                  float* __restrict__ out) {
  const int b = blockIdx.x;
  const int chunk = blockIdx.y;
  const int tid = threadIdx.x;
  const int wid = tid >> 6;
  const int lane = tid & 63;
  const float* base = logits + b * 1024;

  float x[4];
#pragma unroll
  for (int j = 0; j < 4; ++j) x[j] = base[j * 256 + tid];
  float mx = fmaxf(fmaxf(x[0], x[1]), fmaxf(x[2], x[3]));
#pragma unroll
  for (int d = 1; d < 64; d <<= 1) mx = fmaxf(mx, __shfl_xor(mx, d, 64));
  __shared__ float redm[4], reds[4];
  if (lane == 0) redm[wid] = mx;
  __syncthreads();
  mx = fmaxf(fmaxf(redm[0], redm[1]), fmaxf(redm[2], redm[3]));
  float s = 0.f;
#pragma unroll
  for (int j = 0; j < 4; ++j) s += __builtin_amdgcn_exp2f((x[j] - mx) * LOG2E);
#pragma unroll
  for (int d = 1; d < 64; d <<= 1) s += __shfl_xor(s, d, 64);
  if (lane == 0) reds[wid] = s;
  __syncthreads();
  s = reds[0] + reds[1] + reds[2] + reds[3];
  const float inv = 1.0f / s;

  if (chunk == 0) {
#pragma unroll
    for (int j = 0; j < 4; ++j)
      out[65536 + b * 1024 + j * 256 + tid] =
          __builtin_amdgcn_exp2f((x[j] - mx) * LOG2E) * inv;
  }

  __shared__ float p[128];
  const int l0 = chunk * 128;
  if (tid < 128)
    p[tid] = __builtin_amdgcn_exp2f((base[l0 + tid] - mx) * LOG2E) * inv;
  __syncthreads();

  const f32x4* vb = (const f32x4*)(vis + ((size_t)b * 1024 + (size_t)l0) * 1024) + tid;
  f32x4 acc0 = (f32x4){0.f, 0.f, 0.f, 0.f};
  f32x4 acc1 = (f32x4){0.f, 0.f, 0.f, 0.f};
#pragma unroll 4
  for (int l = 0; l < 128; l += 2) {
    acc0 += vb[(size_t)l * 256] * p[l];
    acc1 += vb[(size_t)(l + 1) * 256] * p[l + 1];
  }
  f32x4 acc = acc0 + acc1;
  float* o = out + b * 1024 + tid * 4;
  atomicAdd(o + 0, acc[0]);
  atomicAdd(o + 1, acc[1]);
  atomicAdd(o + 2, acc[2]);
  atomicAdd(o + 3, acc[3]);
}

extern "C" void kernel_launch(void* const* d_in, const int* in_sizes, int n_in,
                              void* d_out, int out_size, void* d_ws, size_t ws_size,
                              hipStream_t stream) {
  const float* vis = (const float*)d_in[0];    // [64][1024][1024]
  const float* dec = (const float*)d_in[1];    // [64][512]
  const float* Wenc = (const float*)d_in[2];   // [1024][512]
  const float* benc = (const float*)d_in[3];   // [512]
  const float* Wdec = (const float*)d_in[4];   // [512][512]
  const float* bdec = (const float*)d_in[5];   // [512]
  const float* wfull = (const float*)d_in[6];  // [512]
  // d_in[7] = b_full: softmax-shift-invariant -> unused.
  float* out = (float*)d_out;                  // [65536 att_output | 65536 att_scores]
  char* ws = (char*)d_ws;
  unsigned short* Wst = (unsigned short*)ws;               // 1 MB bf16-packed W_enc
  float* dproj = (float*)(ws + (1 << 20));                 // 128 KB
  float* logits = (float*)(ws + (1 << 20) + (128 << 10));  // 256 KB

  hipLaunchKernelGGL(k01_prep, dim3(512), dim3(256), 0, stream,
                     Wenc, Wst, dec, Wdec, bdec, benc, dproj, logits, out);
  hipLaunchKernelGGL(k2_fused_gemm, dim3(512), dim3(512), 0, stream,
                     vis, Wst, dproj, wfull, logits);
  hipLaunchKernelGGL(k34_attout, dim3(64, 8), dim3(256), 0, stream,
                     logits, vis, out);
}